// Round 1
// baseline (853.164 us; speedup 1.0000x reference)
//
#include <hip/hip_runtime.h>
#include <math.h>

#define EPSN 1e-12f
#define EPSS 1e-8f
#define RR 8192
#define DD 256
#define ROWS_PER_WAVE 32

typedef float f4 __attribute__((ext_vector_type(4)));

// XOR butterfly allreduce: all 64 lanes end with the full sum (bit-identical)
__device__ __forceinline__ float wallred(float v) {
#pragma unroll
    for (int o = 32; o > 0; o >>= 1) v += __shfl_xor(v, o, 64);
    return v;
}
__device__ __forceinline__ float wred_sum(float v) {
#pragma unroll
    for (int o = 32; o > 0; o >>= 1) v += __shfl_down(v, o, 64);
    return v;
}
__device__ __forceinline__ float wred_max(float v) {
#pragma unroll
    for (int o = 32; o > 0; o >>= 1) v = fmaxf(v, __shfl_down(v, o, 64));
    return v;
}

__device__ __forceinline__ float bred_sum(float v, float* red) {
    const int lane = threadIdx.x & 63;
    const int w = threadIdx.x >> 6;
    const int nw = blockDim.x >> 6;
    v = wred_sum(v);
    __syncthreads();
    if (lane == 0) red[w] = v;
    __syncthreads();
    float r = red[0];
    for (int i = 1; i < nw; ++i) r += red[i];
    return r;
}
__device__ __forceinline__ float bred_max(float v, float* red) {
    const int lane = threadIdx.x & 63;
    const int w = threadIdx.x >> 6;
    const int nw = blockDim.x >> 6;
    v = wred_max(v);
    __syncthreads();
    if (lane == 0) red[w] = v;
    __syncthreads();
    float r = red[0];
    for (int i = 1; i < nw; ++i) r = fmaxf(r, red[i]);
    return r;
}

// Fused: copy reps->out + cosine sims. One wave per 32-row contiguous chunk
// (32 | 8192 so a chunk never spans batches). qn computed inline per wave
// (amortized over 32 rows) -- no separate prep kernel, no qn workspace.
__global__ __launch_bounds__(256)
void k_copy_sims(const float* __restrict__ reps, const int* __restrict__ qrels,
                 float* __restrict__ out, float* __restrict__ sims, int nrows) {
    const int lane = threadIdx.x & 63;
    const int wid = blockIdx.x * 4 + (threadIdx.x >> 6);
    const long long row0 = (long long)wid * ROWS_PER_WAVE;
    if (row0 >= nrows) return;
    const int b = (int)(row0 >> 13);              // RR = 8192

    int q = qrels[b];
    q = q < 0 ? 0 : (q >= RR ? RR - 1 : q);

    // normalized query vector, held in registers (each lane: one float4 slice)
    const f4* __restrict__ qsrc = (const f4*)(reps + ((size_t)b * RR + q) * DD);
    f4 qv = qsrc[lane];
    float ssq = qv.x * qv.x + qv.y * qv.y + qv.z * qv.z + qv.w * qv.w;
    ssq = wallred(ssq);
    const float qinv = 1.f / fmaxf(sqrtf(ssq), EPSN);
    qv *= qinv;

    const f4* __restrict__ src = (const f4*)reps + (size_t)row0 * (DD / 4);
    f4* __restrict__ dst = (f4*)out + (size_t)row0 * (DD / 4);

    float simreg = 0.f;
#pragma unroll 4
    for (int r = 0; r < ROWS_PER_WAVE; ++r) {
        f4 v = __builtin_nontemporal_load(src + (size_t)r * 64 + lane);
        __builtin_nontemporal_store(v, dst + (size_t)r * 64 + lane);
        float dot = v.x * qv.x + v.y * qv.y + v.z * qv.z + v.w * qv.w;
        float ss  = v.x * v.x + v.y * v.y + v.z * v.z + v.w * v.w;
        dot = wallred(dot);
        ss  = wallred(ss);
        float s = dot / fmaxf(sqrtf(ss), EPSN);
        if (lane == r) simreg = s;                // park row r's sim in lane r
    }
    if (lane < ROWS_PER_WAVE) sims[row0 + lane] = simreg;   // one coalesced store
}

// Per-batch epilogue. Early-out (exact row copy) when mask is empty.
// Full path fuses old passes 2+3: invZ cancels -> weight = e*w*g / (S' + 1e-8*Z).
__global__ __launch_bounds__(256)
void k_epilogue(const float* __restrict__ reps, const float* __restrict__ sims_g,
                const int* __restrict__ qrels,
                const float* __restrict__ p_thr, const float* __restrict__ p_str,
                const float* __restrict__ p_scale, const float* __restrict__ p_temp,
                float* __restrict__ out) {
    __shared__ float s_sims[RR];
    __shared__ float s_w[2048];
    __shared__ int   s_r[2048];
    __shared__ float red[4];
    __shared__ int   s_cnt;

    const int b = blockIdx.x;
    const int tid = threadIdx.x;
    int q = qrels[b];
    q = q < 0 ? 0 : (q >= RR ? RR - 1 : q);

    const float threshold = 1.f / (1.f + expf(-p_thr[0]));

    // pass 1: load sims -> LDS, self-exclude, masked max
    const float* __restrict__ srow = sims_g + (size_t)b * RR;
    float lmax = -INFINITY;
    for (int r = tid; r < RR; r += DD) {
        float s = srow[r];
        if (r == q) s = -1.f;
        s_sims[r] = s;
        if (s > threshold) lmax = fmaxf(lmax, s);
    }
    const float smax = bred_max(lmax, red);
    const size_t o = ((size_t)b * RR + q) * DD + tid;   // tid < DD == blockDim
    if (!(smax > -INFINITY)) {        // no valid neighbor: exact copy of q-row
        out[o] = reps[o];
        return;
    }

    const float strength = 0.2f / (1.f + expf(-p_str[0]));
    const float scale    = p_scale[0];
    float temp = p_temp[0];
    temp = fminf(fmaxf(temp, 0.1f), 10.f);
    const float invT = 1.f / temp;
    const float m = smax * invT;

    // pass 2 (fused): Z = sum e ;  S' = sum e*w*g   (both need m only)
    float lz = 0.f, ls = 0.f;
    for (int r = tid; r < RR; r += DD) {
        float s = s_sims[r];
        if (s > threshold) {
            float e = expf(s * invT - m);
            float w = 1.f / (1.f + expf(-(s - threshold) * 10.f));
            float g = 1.f + scale * s;
            lz += e;
            ls += e * w * g;
        }
    }
    const float Z  = bred_sum(lz, red);
    const float Sp = bred_sum(ls, red);
    const float invden = 1.f / (Sp + EPSS * Z);

    // pass 3: chunked compaction + weighted accumulation (thread tid owns dim tid)
    float acc = 0.f;
    for (int base = 0; base < RR; base += 2048) {
        if (tid == 0) s_cnt = 0;
        __syncthreads();
        for (int r = base + tid; r < base + 2048; r += DD) {
            float s = s_sims[r];
            if (s > threshold) {
                float e = expf(s * invT - m);
                float w = 1.f / (1.f + expf(-(s - threshold) * 10.f));
                float g = 1.f + scale * s;
                int j = atomicAdd(&s_cnt, 1);
                s_r[j] = r;
                s_w[j] = e * w * g * invden;
            }
        }
        __syncthreads();
        const int cnt = s_cnt;
        for (int j = 0; j < cnt; ++j)
            acc += s_w[j] * reps[((size_t)b * RR + s_r[j]) * DD + tid];
        __syncthreads();
    }

    const float qv = reps[o];
    out[o] = (1.f - strength) * qv + strength * acc;
}

extern "C" void kernel_launch(void* const* d_in, const int* in_sizes, int n_in,
                              void* d_out, int out_size, void* d_ws, size_t ws_size,
                              hipStream_t stream) {
    const float* reps    = (const float*)d_in[0];
    const int*   qrels   = (const int*)d_in[1];
    const float* p_thr   = (const float*)d_in[2];
    const float* p_str   = (const float*)d_in[3];
    const float* p_scale = (const float*)d_in[4];
    const float* p_temp  = (const float*)d_in[5];
    float* out = (float*)d_out;

    const int B = (int)(in_sizes[0] / ((long long)RR * DD));   // element-count semantics (baseline-verified)
    float* ws_sims = (float*)d_ws;                             // B*R floats

    const int nrows = B * RR;                                  // 524288
    const int waves = nrows / ROWS_PER_WAVE;                   // 16384
    const int blocks = (waves + 3) / 4;                        // 4096 blocks x 256 thr

    k_copy_sims<<<blocks, 256, 0, stream>>>(reps, qrels, out, ws_sims, nrows);
    k_epilogue<<<B, 256, 0, stream>>>(reps, ws_sims, qrels, p_thr, p_str, p_scale, p_temp, out);
}